// Round 6
// baseline (143.929 us; speedup 1.0000x reference)
//
#include <hip/hip_runtime.h>

// Problem constants
#define BB   8
#define CC   256
#define HH   64
#define WW   64
#define CR   64     // reduced channels
#define NG   32     // groups
#define GC   8      // group_channels
#define KK   25     // 5x5 taps
#define HW   (HH*WW)

typedef __attribute__((ext_vector_type(8))) short short8;   // 8 bf16 = 4 VGPRs
typedef __attribute__((ext_vector_type(4))) float f32x4;    // MFMA C/D

__device__ __forceinline__ unsigned short f2bf(float f) {
    unsigned u = __builtin_bit_cast(unsigned, f);
    u += 0x7FFFu + ((u >> 16) & 1u);          // round-to-nearest-even
    return (unsigned short)(u >> 16);
}

// ---------------------------------------------------------------------------
// prep (fused): blocks [0,256) pack w2 -> bf16 B-frag layout (w2p);
// blocks [256,320) fold BN into w1 -> bf16 A-frag layout (w1a) + b1f.
// ---------------------------------------------------------------------------
__global__ __launch_bounds__(256) void prep_kernel(
    const float* __restrict__ w1, const float* __restrict__ b1,
    const float* __restrict__ gamma, const float* __restrict__ beta,
    const float* __restrict__ mean, const float* __restrict__ var,
    const float* __restrict__ w2,
    unsigned short* __restrict__ w1a, float* __restrict__ b1f,
    unsigned short* __restrict__ w2p)
{
    int gid = blockIdx.x;
    if (gid < 256) {
        int idx = gid * 256 + threadIdx.x;   // 0..65535
        int j  = idx & 7;
        int l  = (idx >> 3) & 63;
        int ki = (idx >> 9) & 1;
        int nt = (idx >> 10) & 1;
        int g  = idx >> 11;
        int nl = nt * 16 + (l & 15);
        int k  = ki * 32 + (l >> 4) * 8 + j;
        float v = (nl < KK) ? w2[(g * KK + nl) * CR + k] : 0.0f;
        w2p[idx] = f2bf(v);
    } else {
        int idx = (gid - 256) * 256 + threadIdx.x;   // 0..16383
        int j  = idx & 7;
        int l  = (idx >> 3) & 63;
        int mt = (idx >> 9) & 3;
        int ki = (idx >> 11) & 7;
        int r  = mt * 16 + (l & 15);
        int c  = ki * 32 + (l >> 4) * 8 + j;
        float scale = gamma[r] * rsqrtf(var[r] + 1e-5f);
        w1a[idx] = f2bf(w1[r * CC + c] * scale);
        if (idx < CR) {
            float s = gamma[idx] * rsqrtf(var[idx] + 1e-5f);
            b1f[idx] = (b1[idx] - mean[idx]) * s + beta[idx];
        }
    }
}

// ---------------------------------------------------------------------------
// conv1 (MFMA): y[px][r] = ReLU6(x[px][c] . w1a[r][c] + b1f[r]) -> bf16
// ybf[b][h][px][r]. (unchanged from round 5)
// ---------------------------------------------------------------------------
__global__ __launch_bounds__(256) void conv1_kernel(
    const float* __restrict__ x, const unsigned short* __restrict__ w1a,
    const float* __restrict__ b1f, unsigned short* __restrict__ ybf)
{
    const int tid  = threadIdx.x;
    const int h    = blockIdx.x;
    const int b    = blockIdx.y;
    const int lane = tid & 63;
    const int wv   = tid >> 6;
    const int l15  = lane & 15;
    const int q    = lane >> 4;
    const int px   = wv * 16 + l15;

    const float*  xc   = x + (size_t)b * CC * HW + h * WW + px;  // + c*HW
    const short8* w1a8 = (const short8*)w1a;

    f32x4 cfr[4];
    #pragma unroll
    for (int mt = 0; mt < 4; ++mt) cfr[mt] = (f32x4){0.f, 0.f, 0.f, 0.f};

    #pragma unroll
    for (int ki = 0; ki < 8; ++ki) {
        short8 bfr;
        #pragma unroll
        for (int j = 0; j < 8; ++j) {
            float v = xc[(ki * 32 + q * 8 + j) * HW];
            bfr[j] = (short)f2bf(v);
        }
        #pragma unroll
        for (int mt = 0; mt < 4; ++mt) {
            short8 afr = w1a8[(ki * 4 + mt) * 64 + lane];
            cfr[mt] = __builtin_amdgcn_mfma_f32_16x16x32_bf16(afr, bfr, cfr[mt], 0, 0, 0);
        }
    }

    unsigned short* yb = ybf + ((size_t)(b * HH + h) * WW + px) * CR;
    #pragma unroll
    for (int mt = 0; mt < 4; ++mt) {
        unsigned pk[2];
        #pragma unroll
        for (int rp = 0; rp < 2; ++rp) {
            float v0 = cfr[mt][rp * 2 + 0] + b1f[mt * 16 + q * 4 + rp * 2 + 0];
            float v1 = cfr[mt][rp * 2 + 1] + b1f[mt * 16 + q * 4 + rp * 2 + 1];
            v0 = fminf(fmaxf(v0, 0.0f), 6.0f);
            v1 = fminf(fmaxf(v1, 0.0f), 6.0f);
            pk[rp] = (unsigned)f2bf(v0) | ((unsigned)f2bf(v1) << 16);
        }
        *(uint2*)(yb + mt * 16 + q * 4) = make_uint2(pk[0], pk[1]);
    }
}

// ---------------------------------------------------------------------------
// invol: zero-shuffle tap scheme.
// Wave task = (group g, 4 output rows h0..h0+3, all 64 w, all 8 ch).
// lane = (wq, ch): wq = lane>>3 owns w-strip [wq*8, wq*8+8); ch = lane&7.
// x window: per row, 12 floats (w0-2..w0+9) in regs via 2 dwordx4 + 2 edge
// dwordx2; w-pad handled by zeroing edge regs (== reference zero-pad).
// 8-row rolling window amortizes row loads over 4 output rows; dj-shifts are
// register indexing. Kern tile (per wave, per h) via 16 MFMA -> LDS
// [t][w] stride 68; reads are b128, broadcast across the 8 ch-lanes.
// Grid: x = hq*8+gs (blockIdx%8 = gs -> one group-set's x channels per XCD).
// ---------------------------------------------------------------------------
__global__ __launch_bounds__(256, 4) void invol_kernel(
    const float* __restrict__ x, const unsigned short* __restrict__ ybf,
    const unsigned short* __restrict__ w2p, const float* __restrict__ b2,
    float* __restrict__ out)
{
    __shared__ float klds[4][32 * 68];    // 34,816 B

    const int tid  = threadIdx.x;
    const int bx   = blockIdx.x;          // hq*8 + gs
    const int hq   = bx >> 3;
    const int gs   = bx & 7;
    const int b    = blockIdx.y;
    const int lane = tid & 63;
    const int wv   = __builtin_amdgcn_readfirstlane(tid >> 6);
    const int g    = gs * 4 + wv;         // uniform
    const int h0   = hq * 4;
    const int wq   = lane >> 3;
    const int ch   = lane & 7;
    const int w0   = wq * 8;
    const int l15  = lane & 15;
    const int q    = lane >> 4;
    float* kw = klds[wv];

    // ---- B fragments + bias init values (loop-invariant) ----
    const short8* w2p8 = (const short8*)w2p;
    short8 bf[2][2];
    #pragma unroll
    for (int nt = 0; nt < 2; ++nt)
        #pragma unroll
        for (int ki = 0; ki < 2; ++ki)
            bf[nt][ki] = w2p8[((g * 2 + nt) * 2 + ki) * 64 + lane];
    float b2v[2];
    #pragma unroll
    for (int nt = 0; nt < 2; ++nt) {
        int t = nt * 16 + l15;
        b2v[nt] = b2[g * KK + min(t, KK - 1)];   // t>=25 cols never read
    }

    // ---- x rolling window: rows hh = h0-2 .. h0+5 -> xw[ridx][12] ----
    float xw[8][12];
    const float* xch = x + (size_t)(b * CC + g * GC + ch) * HW;
    const bool wlo = (wq == 0), whi = (wq == 7);

    #define LOADROW(ridx_)                                                     \
    {                                                                          \
        int hh = h0 - 2 + (ridx_);                                             \
        int hc = min(max(hh, 0), HH - 1);                                      \
        const float* xr = xch + hc * WW;                                       \
        float2 elo = *(const float2*)(xr + max(w0 - 2, 0));                    \
        float4 m0  = *(const float4*)(xr + w0);                                \
        float4 m1  = *(const float4*)(xr + w0 + 4);                            \
        float2 ehi = *(const float2*)(xr + min(w0 + 8, WW - 2));               \
        xw[ridx_][0]  = wlo ? 0.0f : elo.x;                                    \
        xw[ridx_][1]  = wlo ? 0.0f : elo.y;                                    \
        xw[ridx_][2]  = m0.x; xw[ridx_][3] = m0.y;                             \
        xw[ridx_][4]  = m0.z; xw[ridx_][5] = m0.w;                             \
        xw[ridx_][6]  = m1.x; xw[ridx_][7] = m1.y;                             \
        xw[ridx_][8]  = m1.z; xw[ridx_][9] = m1.w;                             \
        xw[ridx_][10] = whi ? 0.0f : ehi.x;                                    \
        xw[ridx_][11] = whi ? 0.0f : ehi.y;                                    \
    }

    LOADROW(0) LOADROW(1) LOADROW(2) LOADROW(3) LOADROW(4)

    #pragma unroll
    for (int ho = 0; ho < 4; ++ho) {
        const int h = h0 + ho;

        // ---- MFMA: kern[t][w] for this h, this group ----
        const unsigned short* yb = ybf + (size_t)(b * HH + h) * WW * CR;
        f32x4 cfr[4][2];
        #pragma unroll
        for (int mt = 0; mt < 4; ++mt)
            #pragma unroll
            for (int nt = 0; nt < 2; ++nt)
                cfr[mt][nt] = (f32x4){b2v[nt], b2v[nt], b2v[nt], b2v[nt]};
        #pragma unroll
        for (int ki = 0; ki < 2; ++ki)
            #pragma unroll
            for (int mt = 0; mt < 4; ++mt) {
                short8 afr = *(const short8*)(yb + (mt * 16 + l15) * CR + ki * 32 + q * 8);
                #pragma unroll
                for (int nt = 0; nt < 2; ++nt)
                    cfr[mt][nt] = __builtin_amdgcn_mfma_f32_16x16x32_bf16(
                        afr, bf[nt][ki], cfr[mt][nt], 0, 0, 0);
            }
        // C -> LDS: klds[t][w], t = nt*16+l15 (0..31), w = mt*16+q*4 (+r)
        #pragma unroll
        for (int mt = 0; mt < 4; ++mt)
            #pragma unroll
            for (int nt = 0; nt < 2; ++nt)
                *(float4*)(&kw[(nt * 16 + l15) * 68 + mt * 16 + q * 4]) =
                    (float4){cfr[mt][nt][0], cfr[mt][nt][1], cfr[mt][nt][2], cfr[mt][nt][3]};

        // ---- taps: oacc[wi] += kern[t][w0+wi] * xw[ho+di][wi+dj] ----
        float oacc[8];
        #pragma unroll
        for (int i = 0; i < 8; ++i) oacc[i] = 0.0f;

        #pragma unroll
        for (int di = 0; di < 5; ++di) {
            int hh = h + di - 2;                   // uniform
            if (hh >= 0 && hh < HH) {
                #pragma unroll
                for (int dj = 0; dj < 5; ++dj) {
                    float4 k0 = *(const float4*)(&kw[(di * 5 + dj) * 68 + w0]);
                    float4 k1 = *(const float4*)(&kw[(di * 5 + dj) * 68 + w0 + 4]);
                    #pragma unroll
                    for (int wi = 0; wi < 4; ++wi) {
                        oacc[wi]     = fmaf(k0[wi], xw[ho + di][wi + dj],     oacc[wi]);
                        oacc[wi + 4] = fmaf(k1[wi], xw[ho + di][wi + 4 + dj], oacc[wi + 4]);
                    }
                }
            }
        }

        float* op = out + ((size_t)(b * CC + g * GC + ch) * HH + h) * WW + w0;
        *(float4*)op       = (float4){oacc[0], oacc[1], oacc[2], oacc[3]};
        *(float4*)(op + 4) = (float4){oacc[4], oacc[5], oacc[6], oacc[7]};

        // load next window row for the following ho
        if (ho == 0) LOADROW(5)
        if (ho == 1) LOADROW(6)
        if (ho == 2) LOADROW(7)
    }
    #undef LOADROW
}

extern "C" void kernel_launch(void* const* d_in, const int* in_sizes, int n_in,
                              void* d_out, int out_size, void* d_ws, size_t ws_size,
                              hipStream_t stream) {
    const float* x     = (const float*)d_in[0];
    const float* w1    = (const float*)d_in[1];
    const float* b1    = (const float*)d_in[2];
    const float* gamma = (const float*)d_in[3];
    const float* beta  = (const float*)d_in[4];
    const float* mean  = (const float*)d_in[5];
    const float* var   = (const float*)d_in[6];
    const float* w2    = (const float*)d_in[7];
    const float* b2    = (const float*)d_in[8];
    float* out = (float*)d_out;

    char* ws = (char*)d_ws;
    unsigned short* w1a = (unsigned short*)ws;                    // 32 KB
    float*          b1f = (float*)(ws + 32768);                   // 256 B
    unsigned short* w2p = (unsigned short*)(ws + 33024);          // 128 KB
    unsigned short* ybf = (unsigned short*)(ws + 164096);         // 4 MB

    prep_kernel<<<320, 256, 0, stream>>>(w1, b1, gamma, beta, mean, var, w2,
                                         w1a, b1f, w2p);
    conv1_kernel<<<dim3(HH, BB), 256, 0, stream>>>(x, w1a, b1f, ybf);
    invol_kernel<<<dim3(128, BB), 256, 0, stream>>>(x, ybf, w2p, b2, out);
}

// Round 7
// 132.898 us; speedup vs baseline: 1.0830x; 1.0830x over previous
//
#include <hip/hip_runtime.h>

// Problem constants
#define BB   8
#define CC   256
#define HH   64
#define WW   64
#define CR   64     // reduced channels
#define NG   32     // groups
#define GC   8      // group_channels
#define KK   25     // 5x5 taps
#define HW   (HH*WW)

typedef __attribute__((ext_vector_type(8))) short short8;   // 8 bf16 = 4 VGPRs
typedef __attribute__((ext_vector_type(4))) float f32x4;    // MFMA C/D

__device__ __forceinline__ unsigned short f2bf(float f) {
    unsigned u = __builtin_bit_cast(unsigned, f);
    u += 0x7FFFu + ((u >> 16) & 1u);          // round-to-nearest-even
    return (unsigned short)(u >> 16);
}

// ---------------------------------------------------------------------------
// prep (fused): blocks [0,256) pack w2 -> bf16 B-frag layout (w2p);
// blocks [256,320) fold BN into w1 -> bf16 A-frag layout (w1a) + b1f.
// ---------------------------------------------------------------------------
__global__ __launch_bounds__(256) void prep_kernel(
    const float* __restrict__ w1, const float* __restrict__ b1,
    const float* __restrict__ gamma, const float* __restrict__ beta,
    const float* __restrict__ mean, const float* __restrict__ var,
    const float* __restrict__ w2,
    unsigned short* __restrict__ w1a, float* __restrict__ b1f,
    unsigned short* __restrict__ w2p)
{
    int gid = blockIdx.x;
    if (gid < 256) {
        int idx = gid * 256 + threadIdx.x;   // 0..65535
        int j  = idx & 7;
        int l  = (idx >> 3) & 63;
        int ki = (idx >> 9) & 1;
        int nt = (idx >> 10) & 1;
        int g  = idx >> 11;
        int nl = nt * 16 + (l & 15);
        int k  = ki * 32 + (l >> 4) * 8 + j;
        float v = (nl < KK) ? w2[(g * KK + nl) * CR + k] : 0.0f;
        w2p[idx] = f2bf(v);
    } else {
        int idx = (gid - 256) * 256 + threadIdx.x;   // 0..16383
        int j  = idx & 7;
        int l  = (idx >> 3) & 63;
        int mt = (idx >> 9) & 3;
        int ki = (idx >> 11) & 7;
        int r  = mt * 16 + (l & 15);
        int c  = ki * 32 + (l >> 4) * 8 + j;
        float scale = gamma[r] * rsqrtf(var[r] + 1e-5f);
        w1a[idx] = f2bf(w1[r * CC + c] * scale);
        if (idx < CR) {
            float s = gamma[idx] * rsqrtf(var[idx] + 1e-5f);
            b1f[idx] = (b1[idx] - mean[idx]) * s + beta[idx];
        }
    }
}

// ---------------------------------------------------------------------------
// conv1 (MFMA): y[px][r] = ReLU6(x[px][c] . w1a[r][c] + b1f[r]) -> bf16
// ybf[b][h][px][r]. (unchanged)
// ---------------------------------------------------------------------------
__global__ __launch_bounds__(256) void conv1_kernel(
    const float* __restrict__ x, const unsigned short* __restrict__ w1a,
    const float* __restrict__ b1f, unsigned short* __restrict__ ybf)
{
    const int tid  = threadIdx.x;
    const int h    = blockIdx.x;
    const int b    = blockIdx.y;
    const int lane = tid & 63;
    const int wv   = tid >> 6;
    const int l15  = lane & 15;
    const int q    = lane >> 4;
    const int px   = wv * 16 + l15;

    const float*  xc   = x + (size_t)b * CC * HW + h * WW + px;  // + c*HW
    const short8* w1a8 = (const short8*)w1a;

    f32x4 cfr[4];
    #pragma unroll
    for (int mt = 0; mt < 4; ++mt) cfr[mt] = (f32x4){0.f, 0.f, 0.f, 0.f};

    #pragma unroll
    for (int ki = 0; ki < 8; ++ki) {
        short8 bfr;
        #pragma unroll
        for (int j = 0; j < 8; ++j) {
            float v = xc[(ki * 32 + q * 8 + j) * HW];
            bfr[j] = (short)f2bf(v);
        }
        #pragma unroll
        for (int mt = 0; mt < 4; ++mt) {
            short8 afr = w1a8[(ki * 4 + mt) * 64 + lane];
            cfr[mt] = __builtin_amdgcn_mfma_f32_16x16x32_bf16(afr, bfr, cfr[mt], 0, 0, 0);
        }
    }

    unsigned short* yb = ybf + ((size_t)(b * HH + h) * WW + px) * CR;
    #pragma unroll
    for (int mt = 0; mt < 4; ++mt) {
        unsigned pk[2];
        #pragma unroll
        for (int rp = 0; rp < 2; ++rp) {
            float v0 = cfr[mt][rp * 2 + 0] + b1f[mt * 16 + q * 4 + rp * 2 + 0];
            float v1 = cfr[mt][rp * 2 + 1] + b1f[mt * 16 + q * 4 + rp * 2 + 1];
            v0 = fminf(fmaxf(v0, 0.0f), 6.0f);
            v1 = fminf(fmaxf(v1, 0.0f), 6.0f);
            pk[rp] = (unsigned)f2bf(v0) | ((unsigned)f2bf(v1) << 16);
        }
        *(uint2*)(yb + mt * 16 + q * 4) = make_uint2(pk[0], pk[1]);
    }
}

// ---------------------------------------------------------------------------
// invol: zero-shuffle tap scheme (R6 structure).
// ONLY change vs R6: __launch_bounds__(256, 2) -> 256-VGPR cap so the
// xw[8][12] rolling window stays in registers (R6's (256,4)/128-cap spilled
// it to scratch: VGPR=64, +25 MB WRITE_SIZE, VALUBusy 8%).
// 2 blocks/CU; 8 waves/CU saturate the CU-shared LDS pipe for kern reads.
// ---------------------------------------------------------------------------
__global__ __launch_bounds__(256, 2) void invol_kernel(
    const float* __restrict__ x, const unsigned short* __restrict__ ybf,
    const unsigned short* __restrict__ w2p, const float* __restrict__ b2,
    float* __restrict__ out)
{
    __shared__ float klds[4][32 * 68];    // 34,816 B

    const int tid  = threadIdx.x;
    const int bx   = blockIdx.x;          // hq*8 + gs
    const int hq   = bx >> 3;
    const int gs   = bx & 7;
    const int b    = blockIdx.y;
    const int lane = tid & 63;
    const int wv   = __builtin_amdgcn_readfirstlane(tid >> 6);
    const int g    = gs * 4 + wv;         // uniform
    const int h0   = hq * 4;
    const int wq   = lane >> 3;
    const int ch   = lane & 7;
    const int w0   = wq * 8;
    const int l15  = lane & 15;
    const int q    = lane >> 4;
    float* kw = klds[wv];

    // ---- B fragments + bias init values (loop-invariant) ----
    const short8* w2p8 = (const short8*)w2p;
    short8 bf[2][2];
    #pragma unroll
    for (int nt = 0; nt < 2; ++nt)
        #pragma unroll
        for (int ki = 0; ki < 2; ++ki)
            bf[nt][ki] = w2p8[((g * 2 + nt) * 2 + ki) * 64 + lane];
    float b2v[2];
    #pragma unroll
    for (int nt = 0; nt < 2; ++nt) {
        int t = nt * 16 + l15;
        b2v[nt] = b2[g * KK + min(t, KK - 1)];   // t>=25 cols never read
    }

    // ---- x rolling window: rows hh = h0-2 .. h0+5 -> xw[ridx][12] ----
    float xw[8][12];
    const float* xch = x + (size_t)(b * CC + g * GC + ch) * HW;
    const bool wlo = (wq == 0), whi = (wq == 7);

    #define LOADROW(ridx_)                                                     \
    {                                                                          \
        int hh = h0 - 2 + (ridx_);                                             \
        int hc = min(max(hh, 0), HH - 1);                                      \
        const float* xr = xch + hc * WW;                                       \
        float2 elo = *(const float2*)(xr + max(w0 - 2, 0));                    \
        float4 m0  = *(const float4*)(xr + w0);                                \
        float4 m1  = *(const float4*)(xr + w0 + 4);                            \
        float2 ehi = *(const float2*)(xr + min(w0 + 8, WW - 2));               \
        xw[ridx_][0]  = wlo ? 0.0f : elo.x;                                    \
        xw[ridx_][1]  = wlo ? 0.0f : elo.y;                                    \
        xw[ridx_][2]  = m0.x; xw[ridx_][3] = m0.y;                             \
        xw[ridx_][4]  = m0.z; xw[ridx_][5] = m0.w;                             \
        xw[ridx_][6]  = m1.x; xw[ridx_][7] = m1.y;                             \
        xw[ridx_][8]  = m1.z; xw[ridx_][9] = m1.w;                             \
        xw[ridx_][10] = whi ? 0.0f : ehi.x;                                    \
        xw[ridx_][11] = whi ? 0.0f : ehi.y;                                    \
    }

    LOADROW(0) LOADROW(1) LOADROW(2) LOADROW(3) LOADROW(4)

    #pragma unroll
    for (int ho = 0; ho < 4; ++ho) {
        const int h = h0 + ho;

        // ---- MFMA: kern[t][w] for this h, this group ----
        const unsigned short* yb = ybf + (size_t)(b * HH + h) * WW * CR;
        f32x4 cfr[4][2];
        #pragma unroll
        for (int mt = 0; mt < 4; ++mt)
            #pragma unroll
            for (int nt = 0; nt < 2; ++nt)
                cfr[mt][nt] = (f32x4){b2v[nt], b2v[nt], b2v[nt], b2v[nt]};
        #pragma unroll
        for (int ki = 0; ki < 2; ++ki)
            #pragma unroll
            for (int mt = 0; mt < 4; ++mt) {
                short8 afr = *(const short8*)(yb + (mt * 16 + l15) * CR + ki * 32 + q * 8);
                #pragma unroll
                for (int nt = 0; nt < 2; ++nt)
                    cfr[mt][nt] = __builtin_amdgcn_mfma_f32_16x16x32_bf16(
                        afr, bf[nt][ki], cfr[mt][nt], 0, 0, 0);
            }
        // C -> LDS: klds[t][w], t = nt*16+l15 (0..31), w = mt*16+q*4 (+r)
        #pragma unroll
        for (int mt = 0; mt < 4; ++mt)
            #pragma unroll
            for (int nt = 0; nt < 2; ++nt)
                *(float4*)(&kw[(nt * 16 + l15) * 68 + mt * 16 + q * 4]) =
                    (float4){cfr[mt][nt][0], cfr[mt][nt][1], cfr[mt][nt][2], cfr[mt][nt][3]};

        // ---- taps: oacc[wi] += kern[t][w0+wi] * xw[ho+di][wi+dj] ----
        float oacc[8];
        #pragma unroll
        for (int i = 0; i < 8; ++i) oacc[i] = 0.0f;

        #pragma unroll
        for (int di = 0; di < 5; ++di) {
            int hh = h + di - 2;                   // uniform
            if (hh >= 0 && hh < HH) {
                #pragma unroll
                for (int dj = 0; dj < 5; ++dj) {
                    float4 k0 = *(const float4*)(&kw[(di * 5 + dj) * 68 + w0]);
                    float4 k1 = *(const float4*)(&kw[(di * 5 + dj) * 68 + w0 + 4]);
                    #pragma unroll
                    for (int wi = 0; wi < 4; ++wi) {
                        oacc[wi]     = fmaf(k0[wi], xw[ho + di][wi + dj],     oacc[wi]);
                        oacc[wi + 4] = fmaf(k1[wi], xw[ho + di][wi + 4 + dj], oacc[wi + 4]);
                    }
                }
            }
        }

        float* op = out + ((size_t)(b * CC + g * GC + ch) * HH + h) * WW + w0;
        *(float4*)op       = (float4){oacc[0], oacc[1], oacc[2], oacc[3]};
        *(float4*)(op + 4) = (float4){oacc[4], oacc[5], oacc[6], oacc[7]};

        // load next window row for the following ho
        if (ho == 0) LOADROW(5)
        if (ho == 1) LOADROW(6)
        if (ho == 2) LOADROW(7)
    }
    #undef LOADROW
}

extern "C" void kernel_launch(void* const* d_in, const int* in_sizes, int n_in,
                              void* d_out, int out_size, void* d_ws, size_t ws_size,
                              hipStream_t stream) {
    const float* x     = (const float*)d_in[0];
    const float* w1    = (const float*)d_in[1];
    const float* b1    = (const float*)d_in[2];
    const float* gamma = (const float*)d_in[3];
    const float* beta  = (const float*)d_in[4];
    const float* mean  = (const float*)d_in[5];
    const float* var   = (const float*)d_in[6];
    const float* w2    = (const float*)d_in[7];
    const float* b2    = (const float*)d_in[8];
    float* out = (float*)d_out;

    char* ws = (char*)d_ws;
    unsigned short* w1a = (unsigned short*)ws;                    // 32 KB
    float*          b1f = (float*)(ws + 32768);                   // 256 B
    unsigned short* w2p = (unsigned short*)(ws + 33024);          // 128 KB
    unsigned short* ybf = (unsigned short*)(ws + 164096);         // 4 MB

    prep_kernel<<<320, 256, 0, stream>>>(w1, b1, gamma, beta, mean, var, w2,
                                         w1a, b1f, w2p);
    conv1_kernel<<<dim3(HH, BB), 256, 0, stream>>>(x, w1a, b1f, ybf);
    invol_kernel<<<dim3(128, BB), 256, 0, stream>>>(x, ybf, w2p, b2, out);
}